// Round 11
// baseline (872.774 us; speedup 1.0000x reference)
//
#include <hip/hip_runtime.h>
#include <hip/hip_bf16.h>
#include <hip/hip_fp16.h>

// ============================================================================
// GCN forward. Edges bucketed by dst (128 nodes/bucket, fixed-capacity slots,
// no hist/scan/CSR-placement). Each layer = one kernel, one block per bucket:
//   init : LDS acc rows seeded with the node's self row (hs[d]), dinv cached.
//   edge : EDGE-PARALLEL gather - each thread stages 16 packed edge words
//          (coalesced) then runs 16 independent gather chains, accumulating
//          into LDS fp32 via atomicAdd (ds_add_f32). High MLP per thread.
//   dense: R10's conflict-free LDS-weight structure (j-split / f-split with
//          octet __shfl_xor exchange), reading aggregates from LDS (row
//          strides 28/36/20/4 so consecutive rows land on distinct banks).
//
// Algebra: A_hat(xW) = (A_hat x)W, normalization factored as
//   out[d] = dinv[d] * ( sum_{s in N(d)} hs[s] + hs[d] ) + b,  hs = h*dinv[row]
// hs tables fp16 (fp32 accumulation): xs=4.8MB, h2s=6.4MB, h3s=3.2MB.
// ============================================================================

#define NBUCK_SHIFT 7            // 128 nodes per bucket
#define CAP         3072         // bucket capacity (avg 2048, sigma ~45)
#define PART_CHUNK  4096         // edges per partition block (256 thr x 16)

// ---------------- init per-bucket cursors to fixed bases ----------------
__global__ void init_gcur_kernel(int* __restrict__ gcur, int nbuck) {
    int i = blockIdx.x * 256 + threadIdx.x;
    if (i < nbuck) gcur[i] = i * CAP;
}

// ---------------- partition edges into fixed-capacity buckets ----------------
// staged word: (src << 8) | (dst & 127)
__global__ __launch_bounds__(256) void partition_kernel(const int* __restrict__ src,
                                                        const int* __restrict__ dst,
                                                        int* __restrict__ gcur,
                                                        unsigned int* __restrict__ bucketed,
                                                        int n_edges, int nbuck) {
    __shared__ int cnt[1024];
    __shared__ int bbase[1024];
    const int t = threadIdx.x;
    for (int i = t; i < 1024; i += 256) cnt[i] = 0;
    __syncthreads();
    long long start = (long long)blockIdx.x * PART_CHUNK;
    int sv[16], dv[16], bv[16];
#pragma unroll
    for (int k = 0; k < 16; ++k) {
        long long e = start + (long long)k * 256 + t;
        bool ok = e < n_edges;
        sv[k] = ok ? src[e] : 0;
        dv[k] = ok ? dst[e] : 0;
        bv[k] = ok ? (dv[k] >> NBUCK_SHIFT) : -1;
        if (ok) atomicAdd(&cnt[bv[k]], 1);
    }
    __syncthreads();
    for (int i = t; i < nbuck; i += 256) {
        int c = cnt[i];
        bbase[i] = c ? atomicAdd(&gcur[i], c) : 0;
    }
    __syncthreads();
    for (int i = t; i < 1024; i += 256) cnt[i] = 0;   // reuse as running cursor
    __syncthreads();
#pragma unroll
    for (int k = 0; k < 16; ++k) {
        if (bv[k] >= 0) {
            int pos = bbase[bv[k]] + atomicAdd(&cnt[bv[k]], 1);
            bucketed[pos] = ((unsigned int)sv[k] << 8) | (unsigned int)(dv[k] & 127);
        }
    }
}

// ---------------- helpers ----------------
__device__ inline float4 pack8_dev(const float* v) {
    float4 out;
    __half2* h2 = reinterpret_cast<__half2*>(&out);
#pragma unroll
    for (int j = 0; j < 4; ++j) h2[j] = __floats2half2_rn(v[2 * j], v[2 * j + 1]);
    return out;
}
__device__ inline void set8(float* row, float4 raw) {
    const __half2* hh = reinterpret_cast<const __half2*>(&raw);
#pragma unroll
    for (int j = 0; j < 4; ++j) {
        float2 v = __half22float2(hh[j]);
        row[2 * j]     = v.x;
        row[2 * j + 1] = v.y;
    }
}
__device__ inline void atomic_acc8(float* row, float4 raw) {
    const __half2* hh = reinterpret_cast<const __half2*>(&raw);
#pragma unroll
    for (int j = 0; j < 4; ++j) {
        float2 v = __half22float2(hh[j]);
        atomicAdd(row + 2 * j,     v.x);
        atomicAdd(row + 2 * j + 1, v.y);
    }
}

// ---------------- prep: per-bucket degree -> dinv, xs = half(x*dinv) pad 24 --
__global__ __launch_bounds__(256) void prep_kernel(const unsigned int* __restrict__ bucketed,
                                                   const int* __restrict__ gcur,
                                                   const float* __restrict__ x,
                                                   float* __restrict__ dinv,
                                                   __half* __restrict__ xs, int n) {
    __shared__ int ldeg[128];
    const int b = blockIdx.x;
    const int t = threadIdx.x;
    if (t < 128) ldeg[t] = 0;
    __syncthreads();
    const int beg = b * CAP, end = gcur[b];
    for (int e = beg + t; e < end; e += 256)
        atomicAdd(&ldeg[bucketed[e] & 127u], 1);
    __syncthreads();
    if (t < 128) {
        int node = (b << NBUCK_SHIFT) + t;
        if (node < n) {
            float di = rsqrtf((float)ldeg[t] + 1.0f);   // +1 self-loop
            dinv[node] = di;
            const float* xr = x + (long long)node * 18;
            float vv[24];
#pragma unroll
            for (int k = 0; k < 18; ++k) vv[k] = xr[k] * di;
#pragma unroll
            for (int k = 18; k < 24; ++k) vv[k] = 0.0f;
            float4* o = reinterpret_cast<float4*>(xs + (long long)node * 24);
            o[0] = pack8_dev(vv);
            o[1] = pack8_dev(vv + 8);
            o[2] = pack8_dev(vv + 16);
        }
    }
}

// ---------------- fused layer 1+2 (block = bucket of 128 nodes) -------------
// acc stride 28 (rows 112B, 16B-aligned; consecutive rows distinct banks).
__global__ __launch_bounds__(256) void layer12_kernel(
    const __half* __restrict__ xs, const float* __restrict__ dinv,
    const unsigned int* __restrict__ bucketed, const int* __restrict__ gcur,
    const float* __restrict__ W1, const float* __restrict__ b1,
    const float* __restrict__ W2, __half* __restrict__ h2s, int n) {
    __shared__ float sW1[18 * 64];
    __shared__ float sB1[64];
    __shared__ float sW2[64 * 32];
    __shared__ float acc[128 * 28];
    __shared__ float ldv[128];
    const int b = blockIdx.x;
    const int t = threadIdx.x;
    for (int i = t; i < 18 * 64; i += 256) sW1[i] = W1[i];
    for (int i = t; i < 64; i += 256) sB1[i] = b1[i];
    for (int i = t; i < 64 * 32; i += 256) sW2[i] = W2[i];
    // init acc rows with self row
    if (t < 128) {
        int node = (b << NBUCK_SHIFT) + t;
        float* row = &acc[t * 28];
        if (node < n) {
            ldv[t] = dinv[node];
            const float4* pp = reinterpret_cast<const float4*>(xs + (long long)node * 24);
            set8(row, pp[0]);
            set8(row + 8, pp[1]);
            float4 r2 = pp[2];
            float2 v = __half22float2(reinterpret_cast<const __half2*>(&r2)[0]);
            row[16] = v.x; row[17] = v.y; row[18] = 0.0f; row[19] = 0.0f;
        } else {
            ldv[t] = 1.0f;
#pragma unroll
            for (int k = 0; k < 20; ++k) row[k] = 0.0f;
        }
    }
    __syncthreads();

    // ---- edge-parallel gather ----
    const int beg = b * CAP, end = gcur[b];
    for (int base = beg; base < end; base += 4096) {
        unsigned pk[16];
#pragma unroll
        for (int k = 0; k < 16; ++k) {
            int e = base + (k << 8) + t;
            pk[k] = (e < end) ? bucketed[e] : 0xFFFFFFFFu;
        }
#pragma unroll
        for (int k = 0; k < 16; ++k) {
            if (pk[k] != 0xFFFFFFFFu) {
                int s  = (int)(pk[k] >> 8);
                int ld = (int)(pk[k] & 127u);
                const float4* pp = reinterpret_cast<const float4*>(xs + (long long)s * 24);
                float4 r0 = pp[0], r1 = pp[1], r2 = pp[2];
                float* row = &acc[ld * 28];
                atomic_acc8(row, r0);
                atomic_acc8(row + 8, r1);
                float2 v = __half22float2(reinterpret_cast<const __half2*>(&r2)[0]);
                atomicAdd(row + 16, v.x);
                atomicAdd(row + 17, v.y);
            }
        }
    }
    __syncthreads();

    // ---- dense phase: 4 passes x 32 nodes, 8 lanes/node (R10 structure) ----
    const float4* sW1v = reinterpret_cast<const float4*>(sW1);
    const float4* sW2v = reinterpret_cast<const float4*>(sW2);
    const int l8 = t & 7;
#pragma unroll
    for (int p = 0; p < 4; ++p) {
        int ldn = (p << 5) + (t >> 3);
        int node = (b << NBUCK_SHIFT) + ldn;
        if (node >= n) continue;
        float di = ldv[ldn];
        float a[20];
        {
            const float4* av = reinterpret_cast<const float4*>(&acc[ldn * 28]);
#pragma unroll
            for (int q = 0; q < 5; ++q) {
                float4 v = av[q];
                a[4 * q] = v.x; a[4 * q + 1] = v.y; a[4 * q + 2] = v.z; a[4 * q + 3] = v.w;
            }
        }
#pragma unroll
        for (int k = 0; k < 18; ++k) a[k] *= di;

        // stage 1: hidden slice j0 = l8*8
        float hid[8];
#pragma unroll
        for (int jj = 0; jj < 8; ++jj) hid[jj] = sB1[l8 * 8 + jj];
#pragma unroll
        for (int k = 0; k < 18; ++k) {
            float ak = a[k];
#pragma unroll
            for (int q = 0; q < 2; ++q) {
                float4 w = sW1v[k * 16 + l8 * 2 + q];
                hid[4 * q]     = fmaf(ak, w.x, hid[4 * q]);
                hid[4 * q + 1] = fmaf(ak, w.y, hid[4 * q + 1]);
                hid[4 * q + 2] = fmaf(ak, w.z, hid[4 * q + 2]);
                hid[4 * q + 3] = fmaf(ak, w.w, hid[4 * q + 3]);
            }
        }
#pragma unroll
        for (int jj = 0; jj < 8; ++jj) hid[jj] = fmaxf(hid[jj], 0.0f);

        // stage 2: f-split (f0 = l8*4), octet shfl exchange
        float out[4] = {0.0f, 0.0f, 0.0f, 0.0f};
#pragma unroll
        for (int jj = 0; jj < 8; ++jj) {
            float hv[8];
            hv[0] = hid[jj];
#pragma unroll
            for (int m = 1; m < 8; ++m) hv[m] = __shfl_xor(hv[0], m);
#pragma unroll
            for (int m = 0; m < 8; ++m) {
                int j = (l8 ^ m) * 8 + jj;
                float4 w = sW2v[j * 8 + l8];
                out[0] = fmaf(hv[m], w.x, out[0]);
                out[1] = fmaf(hv[m], w.y, out[1]);
                out[2] = fmaf(hv[m], w.z, out[2]);
                out[3] = fmaf(hv[m], w.w, out[3]);
            }
        }
        union { float2 f2; __half2 h2[2]; } u;
        u.h2[0] = __floats2half2_rn(out[0] * di, out[1] * di);
        u.h2[1] = __floats2half2_rn(out[2] * di, out[3] * di);
        *reinterpret_cast<float2*>(h2s + (long long)node * 32 + l8 * 4) = u.f2;
    }
}

// ---------------- fused layer 3 (block = bucket) ----------------------------
// acc stride 36.
__global__ __launch_bounds__(256) void layer3_kernel(
    const __half* __restrict__ h2s, const float* __restrict__ dinv,
    const unsigned int* __restrict__ bucketed, const int* __restrict__ gcur,
    const float* __restrict__ b2, const float* __restrict__ W3,
    __half* __restrict__ h3s, int n) {
    __shared__ float sW3[32 * 16];
    __shared__ float sB2[32];
    __shared__ float acc[128 * 36];
    __shared__ float ldv[128];
    const int b = blockIdx.x;
    const int t = threadIdx.x;
    for (int i = t; i < 32 * 16; i += 256) sW3[i] = W3[i];
    for (int i = t; i < 32; i += 256) sB2[i] = b2[i];
    if (t < 128) {
        int node = (b << NBUCK_SHIFT) + t;
        float* row = &acc[t * 36];
        if (node < n) {
            ldv[t] = dinv[node];
            const float4* pp = reinterpret_cast<const float4*>(h2s + (long long)node * 32);
            set8(row, pp[0]); set8(row + 8, pp[1]); set8(row + 16, pp[2]); set8(row + 24, pp[3]);
        } else {
            ldv[t] = 1.0f;
#pragma unroll
            for (int k = 0; k < 32; ++k) row[k] = 0.0f;
        }
    }
    __syncthreads();

    const int beg = b * CAP, end = gcur[b];
    for (int base = beg; base < end; base += 4096) {
        unsigned pk[16];
#pragma unroll
        for (int k = 0; k < 16; ++k) {
            int e = base + (k << 8) + t;
            pk[k] = (e < end) ? bucketed[e] : 0xFFFFFFFFu;
        }
#pragma unroll
        for (int k = 0; k < 16; ++k) {
            if (pk[k] != 0xFFFFFFFFu) {
                int s  = (int)(pk[k] >> 8);
                int ld = (int)(pk[k] & 127u);
                const float4* pp = reinterpret_cast<const float4*>(h2s + (long long)s * 32);
                float4 r0 = pp[0], r1 = pp[1], r2 = pp[2], r3 = pp[3];
                float* row = &acc[ld * 36];
                atomic_acc8(row, r0);
                atomic_acc8(row + 8, r1);
                atomic_acc8(row + 16, r2);
                atomic_acc8(row + 24, r3);
            }
        }
    }
    __syncthreads();

    // dense: lane owns k in [4*l8, 4*l8+4), f-split output f0 = l8*2
    const float2* sW3v = reinterpret_cast<const float2*>(sW3);
    const int l8 = t & 7;
    const int k0 = l8 * 4;
#pragma unroll
    for (int p = 0; p < 4; ++p) {
        int ldn = (p << 5) + (t >> 3);
        int node = (b << NBUCK_SHIFT) + ldn;
        if (node >= n) continue;
        float di = ldv[ldn];
        float k4[4];
#pragma unroll
        for (int j = 0; j < 4; ++j) k4[j] = acc[ldn * 36 + k0 + j];

        float o0 = 0.0f, o1 = 0.0f;
#pragma unroll
        for (int kk = 0; kk < 4; ++kk) {
            float vv[8];
            vv[0] = fmaxf(fmaf(k4[kk], di, sB2[k0 + kk]), 0.0f);
#pragma unroll
            for (int m = 1; m < 8; ++m) vv[m] = __shfl_xor(vv[0], m);
#pragma unroll
            for (int m = 0; m < 8; ++m) {
                int k = (l8 ^ m) * 4 + kk;
                float2 w = sW3v[k * 8 + l8];
                o0 = fmaf(vv[m], w.x, o0);
                o1 = fmaf(vv[m], w.y, o1);
            }
        }
        *reinterpret_cast<__half2*>(h3s + (long long)node * 16 + l8 * 2) =
            __floats2half2_rn(o0 * di, o1 * di);
    }
}

// ---------------- fused layer 4 (block = bucket) ----------------------------
// acc stride 20.
__global__ __launch_bounds__(256) void layer4_kernel(
    const __half* __restrict__ h3s, const float* __restrict__ dinv,
    const unsigned int* __restrict__ bucketed, const int* __restrict__ gcur,
    const float* __restrict__ b3, const float* __restrict__ W4,
    __half* __restrict__ h4s, int n) {
    __shared__ float sW4[32];
    __shared__ float sB3[16];
    __shared__ float acc[128 * 20];
    __shared__ float ldv[128];
    const int b = blockIdx.x;
    const int t = threadIdx.x;
    if (t < 32) sW4[t] = W4[t];
    if (t < 16) sB3[t] = b3[t];
    if (t < 128) {
        int node = (b << NBUCK_SHIFT) + t;
        float* row = &acc[t * 20];
        if (node < n) {
            ldv[t] = dinv[node];
            const float4* pp = reinterpret_cast<const float4*>(h3s + (long long)node * 16);
            set8(row, pp[0]); set8(row + 8, pp[1]);
        } else {
            ldv[t] = 1.0f;
#pragma unroll
            for (int k = 0; k < 16; ++k) row[k] = 0.0f;
        }
    }
    __syncthreads();

    const int beg = b * CAP, end = gcur[b];
    for (int base = beg; base < end; base += 4096) {
        unsigned pk[16];
#pragma unroll
        for (int k = 0; k < 16; ++k) {
            int e = base + (k << 8) + t;
            pk[k] = (e < end) ? bucketed[e] : 0xFFFFFFFFu;
        }
#pragma unroll
        for (int k = 0; k < 16; ++k) {
            if (pk[k] != 0xFFFFFFFFu) {
                int s  = (int)(pk[k] >> 8);
                int ld = (int)(pk[k] & 127u);
                const float4* pp = reinterpret_cast<const float4*>(h3s + (long long)s * 16);
                float4 r0 = pp[0], r1 = pp[1];
                float* row = &acc[ld * 20];
                atomic_acc8(row, r0);
                atomic_acc8(row + 8, r1);
            }
        }
    }
    __syncthreads();

    // dense: lane owns k in [2*l8, 2*l8+2); octet all-reduce of 2 outputs
    const int l8 = t & 7;
    const int k0 = l8 * 2;
#pragma unroll
    for (int p = 0; p < 4; ++p) {
        int ldn = (p << 5) + (t >> 3);
        int node = (b << NBUCK_SHIFT) + ldn;
        if (node >= n) continue;
        float di = ldv[ldn];
        float o0 = 0.0f, o1 = 0.0f;
#pragma unroll
        for (int kk = 0; kk < 2; ++kk) {
            float v = fmaxf(fmaf(acc[ldn * 20 + k0 + kk], di, sB3[k0 + kk]), 0.0f);
            o0 = fmaf(v, sW4[2 * (k0 + kk)], o0);
            o1 = fmaf(v, sW4[2 * (k0 + kk) + 1], o1);
        }
        o0 += __shfl_xor(o0, 1); o0 += __shfl_xor(o0, 2); o0 += __shfl_xor(o0, 4);
        o1 += __shfl_xor(o1, 1); o1 += __shfl_xor(o1, 2); o1 += __shfl_xor(o1, 4);
        if (l8 == 0)
            *reinterpret_cast<__half2*>(h4s + 2LL * node) = __floats2half2_rn(o0 * di, o1 * di);
    }
}

// ---------------- final: F=2 aggregation + log_softmax (block = bucket) ------
// acc stride 4.
__global__ __launch_bounds__(256) void agg2_lsm_kernel(
    const __half* __restrict__ hs, const float* __restrict__ dinv,
    const unsigned int* __restrict__ bucketed, const int* __restrict__ gcur,
    const float* __restrict__ b, float* __restrict__ out, int n) {
    __shared__ float acc[128 * 4];
    __shared__ float ldv[128];
    const int b_ = blockIdx.x;
    const int t = threadIdx.x;
    if (t < 128) {
        int node = (b_ << NBUCK_SHIFT) + t;
        float* row = &acc[t * 4];
        if (node < n) {
            ldv[t] = dinv[node];
            float2 r = __half22float2(*reinterpret_cast<const __half2*>(hs + 2LL * node));
            row[0] = r.x; row[1] = r.y;
        } else {
            ldv[t] = 1.0f;
            row[0] = 0.0f; row[1] = 0.0f;
        }
    }
    __syncthreads();

    const int beg = b_ * CAP, end = gcur[b_];
    for (int base = beg; base < end; base += 4096) {
        unsigned pk[16];
#pragma unroll
        for (int k = 0; k < 16; ++k) {
            int e = base + (k << 8) + t;
            pk[k] = (e < end) ? bucketed[e] : 0xFFFFFFFFu;
        }
#pragma unroll
        for (int k = 0; k < 16; ++k) {
            if (pk[k] != 0xFFFFFFFFu) {
                int s  = (int)(pk[k] >> 8);
                int ld = (int)(pk[k] & 127u);
                float2 r = __half22float2(*reinterpret_cast<const __half2*>(hs + 2LL * s));
                atomicAdd(&acc[ld * 4],     r.x);
                atomicAdd(&acc[ld * 4 + 1], r.y);
            }
        }
    }
    __syncthreads();

    if (t < 128) {
        int node = (b_ << NBUCK_SHIFT) + t;
        if (node < n) {
            float di = ldv[t];
            float a = acc[t * 4] * di + b[0];
            float c = acc[t * 4 + 1] * di + b[1];
            float m = fmaxf(a, c);
            float lse = m + logf(expf(a - m) + expf(c - m));
            *reinterpret_cast<float2*>(out + 2LL * node) = make_float2(a - lse, c - lse);
        }
    }
}

static inline int cdiv_ll(long long a, int b) { return (int)((a + b - 1) / b); }
static inline char* align16(char* p) { return (char*)(((uintptr_t)p + 15) & ~(uintptr_t)15); }

extern "C" void kernel_launch(void* const* d_in, const int* in_sizes, int n_in,
                              void* d_out, int out_size, void* d_ws, size_t ws_size,
                              hipStream_t stream) {
    (void)n_in; (void)out_size; (void)ws_size;

    const float* x  = (const float*)d_in[0];      // [N,18]
    const int*   ei = (const int*)d_in[1];        // [2,E]
    const float* W1 = (const float*)d_in[2];
    const float* b1 = (const float*)d_in[3];
    const float* W2 = (const float*)d_in[4];
    const float* b2 = (const float*)d_in[5];
    const float* W3 = (const float*)d_in[6];
    const float* b3 = (const float*)d_in[7];
    const float* W4 = (const float*)d_in[8];
    const float* b4 = (const float*)d_in[9];

    const int n = in_sizes[0] / 18;               // 100000
    const int E = in_sizes[1] / 2;                // 1600000
    const int* src = ei;
    const int* dst = ei + E;
    const int nbuck = (n + 127) >> NBUCK_SHIFT;   // 782

    // ---- workspace layout (16B-aligned regions) ----
    char* p = (char*)d_ws;
    int*    gcur       = (int*)p;            p = align16(p + 1024 * 4);
    unsigned int* bucketed = (unsigned int*)p; p = align16(p + (size_t)nbuck * CAP * 4); // 9.6MB
    float*  dinv       = (float*)p;          p = align16(p + (size_t)n * 4);
    __half* xs         = (__half*)p;         p = align16(p + (size_t)n * 24 * 2);  // 4.8MB
    __half* h2s        = (__half*)p;         p = align16(p + (size_t)n * 32 * 2);  // 6.4MB
    __half* h3s        = (__half*)p;         p = align16(p + (size_t)n * 16 * 2);  // 3.2MB
    __half* h4s        = (__half*)p;         p = align16(p + (size_t)n * 2 * 2);   // 0.4MB

    const int B = 256;

    // ---- bucket edges by dst (no hist/scan/CSR placement) ----
    init_gcur_kernel<<<cdiv_ll(nbuck, B), B, 0, stream>>>(gcur, nbuck);
    partition_kernel<<<cdiv_ll(E, PART_CHUNK), B, 0, stream>>>(src, dst, gcur, bucketed, E, nbuck);
    prep_kernel<<<nbuck, B, 0, stream>>>(bucketed, gcur, x, dinv, xs, n);

    // ---- fused edge-parallel layer pipeline (1 block per bucket) ----
    layer12_kernel<<<nbuck, B, 0, stream>>>(xs, dinv, bucketed, gcur, W1, b1, W2, h2s, n);
    layer3_kernel<<<nbuck, B, 0, stream>>>(h2s, dinv, bucketed, gcur, b2, W3, h3s, n);
    layer4_kernel<<<nbuck, B, 0, stream>>>(h3s, dinv, bucketed, gcur, b3, W4, h4s, n);
    agg2_lsm_kernel<<<nbuck, B, 0, stream>>>(h4s, dinv, bucketed, gcur, b4, (float*)d_out, n);
}

// Round 12
// 206.582 us; speedup vs baseline: 4.2248x; 4.2248x over previous
//
#include <hip/hip_runtime.h>
#include <hip/hip_bf16.h>
#include <hip/hip_fp16.h>

// ============================================================================
// GCN forward. CSR-by-dst via fixed-capacity bucketed counting sort (no
// histogram/scan); fused gather+dense layer kernels, 8 lanes/node:
//   - gather: edge-split across 8 lanes, __shfl_xor (DPP/swizzle) combine,
//     register accumulation (NO LDS atomics - R11 showed those are 10x slow).
//   - dense: LDS weights via ds_read_b128/b64, conflict-free lane->bank maps;
//     hidden/k values exchanged intra-octet via __shfl_xor(1..7).
//   - all gather tables have 64B-line-aligned rows: xs padded 18->32 halves
//     (64B), h2s 32 halves (64B), h3s 16 halves (32B) -> exactly 1 cache line
//     per row fetch (48B-stride rows straddled 2 lines half the time).
//
// Algebra: A_hat(xW) = (A_hat x)W, normalization factored as
//   out[d] = dinv[d] * ( sum_{s in N(d)} hs[s] + hs[d] ) + b,  hs = h*dinv[row]
// hs tables fp16 (fp32 accumulation): xs=6.4MB, h2s=6.4MB, h3s=3.2MB.
// ============================================================================

#define NBUCK_SHIFT 8            // 256 nodes per bucket
#define CAP         8192         // bucket capacity (avg 4096, sigma ~64)
#define PART_CHUNK  4096         // edges per partition block (256 thr x 16)

// ---------------- init per-bucket cursors to fixed bases ----------------
__global__ void init_gcur_kernel(int* __restrict__ gcur, int nbuck) {
    int i = threadIdx.x;
    if (i < nbuck) gcur[i] = i * CAP;
}

// ---------------- partition edges into fixed-capacity buckets ----------------
// staged word: (src << 8) | (dst & 255)
__global__ __launch_bounds__(256) void partition_kernel(const int* __restrict__ src,
                                                        const int* __restrict__ dst,
                                                        int* __restrict__ gcur,
                                                        unsigned int* __restrict__ bucketed,
                                                        int n_edges, int nbuck) {
    __shared__ int cnt[512];
    __shared__ int bbase[512];
    const int t = threadIdx.x;
    for (int i = t; i < 512; i += 256) cnt[i] = 0;
    __syncthreads();
    long long start = (long long)blockIdx.x * PART_CHUNK;
    int sv[16], dv[16], bv[16];
#pragma unroll
    for (int k = 0; k < 16; ++k) {
        long long e = start + (long long)k * 256 + t;
        bool ok = e < n_edges;
        sv[k] = ok ? src[e] : 0;
        dv[k] = ok ? dst[e] : 0;
        bv[k] = ok ? (dv[k] >> NBUCK_SHIFT) : -1;
        if (ok) atomicAdd(&cnt[bv[k]], 1);
    }
    __syncthreads();
    for (int i = t; i < nbuck; i += 256) {
        int c = cnt[i];
        bbase[i] = c ? atomicAdd(&gcur[i], c) : 0;
    }
    __syncthreads();
    for (int i = t; i < 512; i += 256) cnt[i] = 0;   // reuse as running cursor
    __syncthreads();
#pragma unroll
    for (int k = 0; k < 16; ++k) {
        if (bv[k] >= 0) {
            int pos = bbase[bv[k]] + atomicAdd(&cnt[bv[k]], 1);
            bucketed[pos] = ((unsigned int)sv[k] << 8) | (unsigned int)(dv[k] & 255);
        }
    }
}

// ---------------- per-bucket CSR finalize + x scale/pad ----------------------
// ends=(beg,end), dinv, sorted_src placement, and xs = half(x*dinv) padded 32.
__device__ inline float4 pack8_dev(const float* v) {
    float4 out;
    __half2* h2 = reinterpret_cast<__half2*>(&out);
#pragma unroll
    for (int j = 0; j < 4; ++j) h2[j] = __floats2half2_rn(v[2 * j], v[2 * j + 1]);
    return out;
}

__global__ __launch_bounds__(256) void csr_kernel(const unsigned int* __restrict__ bucketed,
                                                  const int* __restrict__ gcur,
                                                  const float* __restrict__ x,
                                                  int2* __restrict__ ends,
                                                  float* __restrict__ dinv,
                                                  int* __restrict__ sorted_src,
                                                  __half* __restrict__ xs,
                                                  int n) {
    __shared__ int ldeg[256];
    __shared__ int lscan[256];
    const int b = blockIdx.x;
    const int t = threadIdx.x;
    const int beg = b * CAP;
    const int end = gcur[b];                 // beg + count(bucket b)
    ldeg[t] = 0;
    __syncthreads();
    for (int e = beg + t; e < end; e += 256) {
        unsigned int p = bucketed[e];
        atomicAdd(&ldeg[p & 255u], 1);
    }
    __syncthreads();
    int v = ldeg[t];
    lscan[t] = v;
    __syncthreads();
    for (int off = 1; off < 256; off <<= 1) {
        int xv = (t >= off) ? lscan[t - off] : 0;
        __syncthreads();
        lscan[t] += xv;
        __syncthreads();
    }
    int excl = lscan[t] - v;                 // exclusive scan
    int node = (b << NBUCK_SHIFT) + t;
    float di = rsqrtf((float)v + 1.0f);      // +1 self-loop
    if (node < n) {
        ends[node] = make_int2(beg + excl, beg + excl + v);
        dinv[node] = di;
        // xs row = half(x * di), padded to 32 (64B-aligned row)
        const float* xr = x + (long long)node * 18;
        float vv[32];
#pragma unroll
        for (int k = 0; k < 18; ++k) vv[k] = xr[k] * di;
#pragma unroll
        for (int k = 18; k < 32; ++k) vv[k] = 0.0f;
        float4* o = reinterpret_cast<float4*>(xs + (long long)node * 32);
        o[0] = pack8_dev(vv);
        o[1] = pack8_dev(vv + 8);
        o[2] = pack8_dev(vv + 16);
        o[3] = pack8_dev(vv + 24);
    }
    __syncthreads();
    lscan[t] = beg + excl;                   // reuse as placement cursor
    __syncthreads();
    for (int e = beg + t; e < end; e += 256) {
        unsigned int p = bucketed[e];
        int pos = atomicAdd(&lscan[p & 255u], 1);
        sorted_src[pos] = (int)(p >> 8);
    }
}

// ---------------- helpers ----------------
__device__ inline void acc8(float* acc, float4 raw) {
    const __half2* h2 = reinterpret_cast<const __half2*>(&raw);
#pragma unroll
    for (int j = 0; j < 4; ++j) {
        float2 v = __half22float2(h2[j]);
        acc[2 * j]     += v.x;
        acc[2 * j + 1] += v.y;
    }
}

// ---------------- fused layer 1+2 (8 lanes/node) ----------------------------
// gather(18 of 32-stride rows, edge-split) -> allreduce -> 18->64 relu
// (j-split 8, b128 LDS) -> 64->32 (f-split 8, octet shfl, b128 LDS).
__global__ __launch_bounds__(256) void layer12_kernel(
    const __half* __restrict__ xs, const float* __restrict__ dinv,
    const int* __restrict__ sorted_src, const int2* __restrict__ ends,
    const float* __restrict__ W1, const float* __restrict__ b1,
    const float* __restrict__ W2, __half* __restrict__ h2s, int n) {
    __shared__ float sW1[18 * 64];   // j-stride 8 -> 2-way (free)
    __shared__ float sB1[64];
    __shared__ float sW2[64 * 32];   // f-stride 4 -> banks partitioned, clean
    for (int i = threadIdx.x; i < 18 * 64; i += 256) sW1[i] = W1[i];
    for (int i = threadIdx.x; i < 64; i += 256) sB1[i] = b1[i];
    for (int i = threadIdx.x; i < 64 * 32; i += 256) sW2[i] = W2[i];
    __syncthreads();
    const float4* sW1v = reinterpret_cast<const float4*>(sW1);
    const float4* sW2v = reinterpret_cast<const float4*>(sW2);

    long long gt = (long long)blockIdx.x * 256 + threadIdx.x;
    int node = (int)(gt >> 3);
    int l8   = (int)(gt & 7);
    if (node >= n) return;
    int2 be = ends[node];
    float di = dinv[node];

    // ---- gather (edge-split over 8 lanes); rows 64B-aligned, 1 line each ----
    float acc[24];
#pragma unroll
    for (int j = 0; j < 24; ++j) acc[j] = 0.0f;
    if (l8 == 7) {   // lane 7 has the fewest edges; give it the self row
        const float4* pp = reinterpret_cast<const float4*>(xs + (long long)node * 32);
        acc8(acc, pp[0]); acc8(acc + 8, pp[1]); acc8(acc + 16, pp[2]);
    }
    for (int e = be.x + l8; e < be.y; e += 8) {
        int s = sorted_src[e];
        const float4* pp = reinterpret_cast<const float4*>(xs + (long long)s * 32);
        acc8(acc, pp[0]); acc8(acc + 8, pp[1]); acc8(acc + 16, pp[2]);
    }
#pragma unroll
    for (int j = 0; j < 18; ++j) {       // all-reduce over octet
        acc[j] += __shfl_xor(acc[j], 1);
        acc[j] += __shfl_xor(acc[j], 2);
        acc[j] += __shfl_xor(acc[j], 4);
        acc[j] *= di;                    // fold *di once here
    }

    // ---- stage 1: hidden slice j0 = l8*8 ----
    const int j0 = l8 * 8;
    float hid[8];
#pragma unroll
    for (int jj = 0; jj < 8; ++jj) hid[jj] = sB1[j0 + jj];
#pragma unroll
    for (int k = 0; k < 18; ++k) {
        float ak = acc[k];
#pragma unroll
        for (int q = 0; q < 2; ++q) {
            float4 w = sW1v[k * 16 + l8 * 2 + q];
            hid[4 * q]     = fmaf(ak, w.x, hid[4 * q]);
            hid[4 * q + 1] = fmaf(ak, w.y, hid[4 * q + 1]);
            hid[4 * q + 2] = fmaf(ak, w.z, hid[4 * q + 2]);
            hid[4 * q + 3] = fmaf(ak, w.w, hid[4 * q + 3]);
        }
    }
#pragma unroll
    for (int jj = 0; jj < 8; ++jj) hid[jj] = fmaxf(hid[jj], 0.0f);

    // ---- stage 2: f-split (f0 = l8*4); hid exchanged via octet shfl ----
    float out[4] = {0.0f, 0.0f, 0.0f, 0.0f};
#pragma unroll
    for (int jj = 0; jj < 8; ++jj) {
        float hv[8];
        hv[0] = hid[jj];
#pragma unroll
        for (int m = 1; m < 8; ++m) hv[m] = __shfl_xor(hv[0], m);
#pragma unroll
        for (int m = 0; m < 8; ++m) {
            int j = (l8 ^ m) * 8 + jj;
            float4 w = sW2v[j * 8 + l8];          // = (j*32 + l8*4)/4
            out[0] = fmaf(hv[m], w.x, out[0]);
            out[1] = fmaf(hv[m], w.y, out[1]);
            out[2] = fmaf(hv[m], w.z, out[2]);
            out[3] = fmaf(hv[m], w.w, out[3]);
        }
    }
    union { float2 f2; __half2 h2[2]; } u;
    u.h2[0] = __floats2half2_rn(out[0] * di, out[1] * di);
    u.h2[1] = __floats2half2_rn(out[2] * di, out[3] * di);
    *reinterpret_cast<float2*>(h2s + (long long)node * 32 + l8 * 4) = u.f2;
}

// ---------------- fused layer 3 (8 lanes/node) ------------------------------
// gather(32) -> reduce-scatter (lane owns 4 k's) -> relu(+b2)
// -> 32->16 f-split (f0=l8*2, b64 LDS, octet shfl) -> lane stores 2 fp16.
__global__ __launch_bounds__(256) void layer3_kernel(
    const __half* __restrict__ h2s, const float* __restrict__ dinv,
    const int* __restrict__ sorted_src, const int2* __restrict__ ends,
    const float* __restrict__ b2, const float* __restrict__ W3,
    __half* __restrict__ h3s, int n) {
    __shared__ float sW3[32 * 16];   // f-stride 2 -> conflict-free b64
    __shared__ float sB2[32];
    for (int i = threadIdx.x; i < 32 * 16; i += 256) sW3[i] = W3[i];
    for (int i = threadIdx.x; i < 32; i += 256) sB2[i] = b2[i];
    __syncthreads();
    const float2* sW3v = reinterpret_cast<const float2*>(sW3);

    long long gt = (long long)blockIdx.x * 256 + threadIdx.x;
    int node = (int)(gt >> 3);
    int l8   = (int)(gt & 7);
    if (node >= n) return;
    int2 be = ends[node];
    float di = dinv[node];

    float acc[32];
#pragma unroll
    for (int j = 0; j < 32; ++j) acc[j] = 0.0f;
    if (l8 == 7) {
        const float4* pp = reinterpret_cast<const float4*>(h2s + (long long)node * 32);
        acc8(acc, pp[0]); acc8(acc + 8, pp[1]); acc8(acc + 16, pp[2]); acc8(acc + 24, pp[3]);
    }
    for (int e = be.x + l8; e < be.y; e += 8) {
        int s = sorted_src[e];
        const float4* pp = reinterpret_cast<const float4*>(h2s + (long long)s * 32);
        acc8(acc, pp[0]); acc8(acc + 8, pp[1]); acc8(acc + 16, pp[2]); acc8(acc + 24, pp[3]);
    }
    // reduce-scatter acc[32] over octet -> lane owns k in [4*l8, 4*l8+4)
    const bool hi4 = (l8 & 4);
    float h16[16];
#pragma unroll
    for (int v = 0; v < 16; ++v) {
        float keep = hi4 ? acc[16 + v] : acc[v];
        float send = hi4 ? acc[v] : acc[16 + v];
        h16[v] = keep + __shfl_xor(send, 4);
    }
    const bool hi2 = (l8 & 2);
    float h8[8];
#pragma unroll
    for (int v = 0; v < 8; ++v) {
        float keep = hi2 ? h16[8 + v] : h16[v];
        float send = hi2 ? h16[v] : h16[8 + v];
        h8[v] = keep + __shfl_xor(send, 2);
    }
    const bool hi1 = (l8 & 1);
    float k4[4];
#pragma unroll
    for (int v = 0; v < 4; ++v) {
        float keep = hi1 ? h8[4 + v] : h8[v];
        float send = hi1 ? h8[v] : h8[4 + v];
        k4[v] = keep + __shfl_xor(send, 1);
    }

    // ---- dense: f-split (f0 = l8*2); k-values exchanged via octet shfl ----
    const int k0 = l8 * 4;
    float o0 = 0.0f, o1 = 0.0f;
#pragma unroll
    for (int kk = 0; kk < 4; ++kk) {
        float vv[8];
        vv[0] = fmaxf(fmaf(k4[kk], di, sB2[k0 + kk]), 0.0f);  // relu(acc*di+b2)
#pragma unroll
        for (int m = 1; m < 8; ++m) vv[m] = __shfl_xor(vv[0], m);
#pragma unroll
        for (int m = 0; m < 8; ++m) {
            int k = (l8 ^ m) * 4 + kk;
            float2 w = sW3v[k * 8 + l8];          // = (k*16 + l8*2)/2
            o0 = fmaf(vv[m], w.x, o0);
            o1 = fmaf(vv[m], w.y, o1);
        }
    }
    *reinterpret_cast<__half2*>(h3s + (long long)node * 16 + l8 * 2) =
        __floats2half2_rn(o0 * di, o1 * di);
}

// ---------------- fused layer 4 (8 lanes/node, tiny weights) -----------------
__global__ __launch_bounds__(256) void layer4_kernel(
    const __half* __restrict__ h3s, const float* __restrict__ dinv,
    const int* __restrict__ sorted_src, const int2* __restrict__ ends,
    const float* __restrict__ b3, const float* __restrict__ W4,
    __half* __restrict__ h4s, int n) {
    __shared__ float sW4[32];
    __shared__ float sB3[16];
    for (int i = threadIdx.x; i < 32; i += 256) sW4[i] = W4[i];
    for (int i = threadIdx.x; i < 16; i += 256) sB3[i] = b3[i];
    __syncthreads();

    long long gt = (long long)blockIdx.x * 256 + threadIdx.x;
    int node = (int)(gt >> 3);
    int l8   = (int)(gt & 7);
    if (node >= n) return;
    int2 be = ends[node];
    float di = dinv[node];

    float acc[16];
#pragma unroll
    for (int j = 0; j < 16; ++j) acc[j] = 0.0f;
    if (l8 == 7) {
        const float4* pp = reinterpret_cast<const float4*>(h3s + (long long)node * 16);
        acc8(acc, pp[0]); acc8(acc + 8, pp[1]);
    }
    for (int e = be.x + l8; e < be.y; e += 8) {
        int s = sorted_src[e];
        const float4* pp = reinterpret_cast<const float4*>(h3s + (long long)s * 16);
        acc8(acc, pp[0]); acc8(acc + 8, pp[1]);
    }
    // reduce-scatter acc[16] over octet -> lane owns k in [2*l8, 2*l8+2)
    const bool hi4 = (l8 & 4);
    float h8[8];
#pragma unroll
    for (int v = 0; v < 8; ++v) {
        float keep = hi4 ? acc[8 + v] : acc[v];
        float send = hi4 ? acc[v] : acc[8 + v];
        h8[v] = keep + __shfl_xor(send, 4);
    }
    const bool hi2 = (l8 & 2);
    float h4v[4];
#pragma unroll
    for (int v = 0; v < 4; ++v) {
        float keep = hi2 ? h8[4 + v] : h8[v];
        float send = hi2 ? h8[v] : h8[4 + v];
        h4v[v] = keep + __shfl_xor(send, 2);
    }
    const bool hi1 = (l8 & 1);
    float k2[2];
#pragma unroll
    for (int v = 0; v < 2; ++v) {
        float keep = hi1 ? h4v[2 + v] : h4v[v];
        float send = hi1 ? h4v[v] : h4v[2 + v];
        k2[v] = keep + __shfl_xor(send, 1);
    }
    const int k0 = l8 * 2;
    float o0 = 0.0f, o1 = 0.0f;
#pragma unroll
    for (int kk = 0; kk < 2; ++kk) {
        float v = fmaxf(fmaf(k2[kk], di, sB3[k0 + kk]), 0.0f);
        o0 = fmaf(v, sW4[2 * (k0 + kk)], o0);
        o1 = fmaf(v, sW4[2 * (k0 + kk) + 1], o1);
    }
    o0 += __shfl_xor(o0, 1); o0 += __shfl_xor(o0, 2); o0 += __shfl_xor(o0, 4);
    o1 += __shfl_xor(o1, 1); o1 += __shfl_xor(o1, 2); o1 += __shfl_xor(o1, 4);
    if (l8 == 0)
        *reinterpret_cast<__half2*>(h4s + 2LL * node) = __floats2half2_rn(o0 * di, o1 * di);
}

// ---------------- final: F=2 aggregation + log_softmax (8 lanes/node) --------
__global__ __launch_bounds__(256) void agg2_lsm_kernel(
    const __half* __restrict__ hs, const float* __restrict__ dinv,
    const int* __restrict__ sorted_src, const int2* __restrict__ ends,
    const float* __restrict__ b, float* __restrict__ out, int n) {
    long long gt = (long long)blockIdx.x * 256 + threadIdx.x;
    int node = (int)(gt >> 3);
    int l8   = (int)(gt & 7);
    if (node >= n) return;
    int2 be = ends[node];
    float ax = 0.0f, ay = 0.0f;
    if (l8 == 7) {
        float2 r = __half22float2(*reinterpret_cast<const __half2*>(hs + 2LL * node));
        ax += r.x; ay += r.y;
    }
    for (int e = be.x + l8; e < be.y; e += 8) {
        int s = sorted_src[e];
        float2 r = __half22float2(*reinterpret_cast<const __half2*>(hs + 2LL * s));
        ax += r.x; ay += r.y;
    }
    ax += __shfl_xor(ax, 1); ax += __shfl_xor(ax, 2); ax += __shfl_xor(ax, 4);
    ay += __shfl_xor(ay, 1); ay += __shfl_xor(ay, 2); ay += __shfl_xor(ay, 4);
    if (l8 == 0) {
        float di = dinv[node];
        float a = ax * di + b[0];
        float c = ay * di + b[1];
        float m = fmaxf(a, c);
        float lse = m + logf(expf(a - m) + expf(c - m));
        float2 r = make_float2(a - lse, c - lse);
        *reinterpret_cast<float2*>(out + 2LL * node) = r;
    }
}

static inline int cdiv_ll(long long a, int b) { return (int)((a + b - 1) / b); }
static inline char* align16(char* p) { return (char*)(((uintptr_t)p + 15) & ~(uintptr_t)15); }

extern "C" void kernel_launch(void* const* d_in, const int* in_sizes, int n_in,
                              void* d_out, int out_size, void* d_ws, size_t ws_size,
                              hipStream_t stream) {
    (void)n_in; (void)out_size; (void)ws_size;

    const float* x  = (const float*)d_in[0];      // [N,18]
    const int*   ei = (const int*)d_in[1];        // [2,E]
    const float* W1 = (const float*)d_in[2];
    const float* b1 = (const float*)d_in[3];
    const float* W2 = (const float*)d_in[4];
    const float* b2 = (const float*)d_in[5];
    const float* W3 = (const float*)d_in[6];
    const float* b3 = (const float*)d_in[7];
    const float* W4 = (const float*)d_in[8];
    const float* b4 = (const float*)d_in[9];

    const int n = in_sizes[0] / 18;               // 100000
    const int E = in_sizes[1] / 2;                // 1600000
    const int* src = ei;
    const int* dst = ei + E;
    const int nbuck = (n + 255) >> NBUCK_SHIFT;   // 391

    // ---- workspace layout (16B-aligned regions) ----
    char* p = (char*)d_ws;
    int*    gcur       = (int*)p;            p = align16(p + 512 * 4);
    int2*   ends       = (int2*)p;           p = align16(p + (size_t)n * 8);
    float*  dinv       = (float*)p;          p = align16(p + (size_t)n * 4);
    int*    sorted_src = (int*)p;            p = align16(p + (size_t)nbuck * CAP * 4);  // 12.8MB padded
    unsigned int* bucketed = (unsigned int*)p; p = align16(p + (size_t)nbuck * CAP * 4); // 12.8MB padded
    __half* xs         = (__half*)p;         p = align16(p + (size_t)n * 32 * 2);  // 6.4MB (64B rows)
    __half* h2s        = (__half*)p;         p = align16(p + (size_t)n * 32 * 2);  // 6.4MB
    __half* h3s        = (__half*)p;         p = align16(p + (size_t)n * 16 * 2);  // 3.2MB
    __half* h4s        = (__half*)p;         p = align16(p + (size_t)n * 2 * 2);   // 0.4MB

    const int B = 256;
    const int NODE8_BLOCKS = cdiv_ll(8LL * n, B);

    // ---- CSR-by-dst via fixed-capacity bucketed sort (no hist/scan) ----
    init_gcur_kernel<<<1, 512, 0, stream>>>(gcur, nbuck);
    partition_kernel<<<cdiv_ll(E, PART_CHUNK), B, 0, stream>>>(src, dst, gcur, bucketed, E, nbuck);
    csr_kernel<<<nbuck, B, 0, stream>>>(bucketed, gcur, x, ends, dinv, sorted_src, xs, n);

    // ---- fused pipeline (8 lanes/node) ----
    layer12_kernel<<<NODE8_BLOCKS, B, 0, stream>>>(xs, dinv, sorted_src, ends, W1, b1, W2, h2s, n);
    layer3_kernel<<<NODE8_BLOCKS, B, 0, stream>>>(h2s, dinv, sorted_src, ends, b2, W3, h3s, n);
    layer4_kernel<<<NODE8_BLOCKS, B, 0, stream>>>(h3s, dinv, sorted_src, ends, b3, W4, h4s, n);
    agg2_lsm_kernel<<<NODE8_BLOCKS, B, 0, stream>>>(h4s, dinv, sorted_src, ends, b4, (float*)d_out, n);
}